// Round 8
// baseline (558.867 us; speedup 1.0000x reference)
//
#include <hip/hip_runtime.h>
#include <hip/hip_bf16.h>

#define N_TOK 2048
#define HIDDEN 1024
#define NHEAD 16
#define DHEAD 64

typedef __attribute__((ext_vector_type(8))) short bf16x8;
typedef __attribute__((ext_vector_type(4))) float f32x4;

#define SB() __builtin_amdgcn_sched_barrier(0)

__device__ inline unsigned short f2bf(float x) {
    __hip_bfloat16 h = __float2bfloat16(x);
    return *reinterpret_cast<unsigned short*>(&h);
}

__device__ inline f32x4 zero4() {
    f32x4 z;
    z[0] = 0.f; z[1] = 0.f; z[2] = 0.f; z[3] = 0.f;
    return z;
}

// ---------------- K0: fused f32 -> bf16 conversion for x, Wq, Wk, Wv ----------------
__global__ void cvt4_kernel(const float* __restrict__ x, const float* __restrict__ wq,
                            const float* __restrict__ wk, const float* __restrict__ wv,
                            unsigned short* __restrict__ dst) {
    int i = blockIdx.x * blockDim.x + threadIdx.x;  // 1310720 float4 jobs
    const float* src;
    int off;
    if (i < 524288)       { src = x;  off = i; }
    else if (i < 786432)  { src = wq; off = i - 524288; }
    else if (i < 1048576) { src = wk; off = i - 786432; }
    else                  { src = wv; off = i - 1048576; }
    float4 v = reinterpret_cast<const float4*>(src)[off];
    ushort4 o;
    o.x = f2bf(v.x); o.y = f2bf(v.y); o.z = f2bf(v.z); o.w = f2bf(v.w);
    reinterpret_cast<ushort4*>(dst)[i] = o;
}

// ---------------- K1: fused QKV GEMM; v-region writes tiled vt directly ----------------
__launch_bounds__(256)
__global__ void gemm_qkv(const unsigned short* __restrict__ xb,
                         const unsigned short* __restrict__ wb,
                         const float* __restrict__ bq, const float* __restrict__ bk,
                         const float* __restrict__ bv,
                         unsigned short* __restrict__ qb, unsigned short* __restrict__ kb,
                         unsigned short* __restrict__ vt) {
    __shared__ unsigned short As[2][128 * 64];
    __shared__ unsigned short Bs[2][128 * 64];
    const int tid = threadIdx.x;
    const int lane = tid & 63;
    const int w = tid >> 6;
    const int wr = w >> 1, wc = w & 1;
    const int rb = blockIdx.y * 128;
    const int cb = blockIdx.x * 128;
    const int r0 = tid >> 3, c0 = tid & 7;

    f32x4 acc[4][4];
    for (int i = 0; i < 4; i++)
        for (int j = 0; j < 4; j++) acc[i][j] = zero4();

    uint4 va[4], vb4[4];
#pragma unroll
    for (int i = 0; i < 4; i++) {
        va[i]  = *reinterpret_cast<const uint4*>(xb + (size_t)(rb + r0 + 32 * i) * HIDDEN + c0 * 8);
        vb4[i] = *reinterpret_cast<const uint4*>(wb + (size_t)(cb + r0 + 32 * i) * HIDDEN + c0 * 8);
    }
#pragma unroll
    for (int i = 0; i < 4; i++) {
        int row = r0 + 32 * i;
        *reinterpret_cast<uint4*>(As[0] + row * 64 + ((c0 ^ (row & 7)) << 3)) = va[i];
        *reinterpret_cast<uint4*>(Bs[0] + row * 64 + ((c0 ^ (row & 7)) << 3)) = vb4[i];
    }
    __syncthreads();
    int cur = 0;

    for (int kt = 0; kt < 16; ++kt) {
        if (kt < 15) {
#pragma unroll
            for (int i = 0; i < 4; i++) {
                va[i]  = *reinterpret_cast<const uint4*>(xb + (size_t)(rb + r0 + 32 * i) * HIDDEN + (kt + 1) * 64 + c0 * 8);
                vb4[i] = *reinterpret_cast<const uint4*>(wb + (size_t)(cb + r0 + 32 * i) * HIDDEN + (kt + 1) * 64 + c0 * 8);
            }
        }
#pragma unroll
        for (int kk = 0; kk < 2; kk++) {
            bf16x8 a[4], b[4];
#pragma unroll
            for (int mi = 0; mi < 4; mi++) {
                int row = wr * 64 + mi * 16 + (lane & 15);
                a[mi] = *reinterpret_cast<const bf16x8*>(As[cur] + row * 64 + (((kk * 4 + (lane >> 4)) ^ (row & 7)) << 3));
            }
#pragma unroll
            for (int ni = 0; ni < 4; ni++) {
                int row = wc * 64 + ni * 16 + (lane & 15);
                b[ni] = *reinterpret_cast<const bf16x8*>(Bs[cur] + row * 64 + (((kk * 4 + (lane >> 4)) ^ (row & 7)) << 3));
            }
#pragma unroll
            for (int mi = 0; mi < 4; mi++)
#pragma unroll
                for (int ni = 0; ni < 4; ni++)
                    acc[mi][ni] = __builtin_amdgcn_mfma_f32_16x16x32_bf16(a[mi], b[ni], acc[mi][ni], 0, 0, 0);
        }
        if (kt < 15) {
#pragma unroll
            for (int i = 0; i < 4; i++) {
                int row = r0 + 32 * i;
                *reinterpret_cast<uint4*>(As[cur ^ 1] + row * 64 + ((c0 ^ (row & 7)) << 3)) = va[i];
                *reinterpret_cast<uint4*>(Bs[cur ^ 1] + row * 64 + ((c0 ^ (row & 7)) << 3)) = vb4[i];
            }
        }
        __syncthreads();
        cur ^= 1;
    }

    const int region = blockIdx.x >> 3;  // 0=q, 1=k, 2=v
    const float* bias = region == 0 ? bq : (region == 1 ? bk : bv);
    unsigned short* dst = region == 0 ? qb : kb;
#pragma unroll
    for (int mi = 0; mi < 4; mi++) {
#pragma unroll
        for (int ni = 0; ni < 4; ni++) {
            int colg = cb + wc * 64 + ni * 16 + (lane & 15);
            int jj = colg & 1023;
            int hh = jj >> 6, d = jj & 63;
            float bval = bias[jj];
#pragma unroll
            for (int r = 0; r < 4; r++) {
                int n = rb + wr * 64 + mi * 16 + ((lane >> 4) << 2) + r;
                unsigned short val = f2bf(acc[mi][ni][r] + bval);
                if (region < 2)
                    dst[((size_t)hh * N_TOK + n) * 64 + d] = val;
                else  // v: tiled layout vt[((h*64 + n/32)*64 + d)*32 + n%32]
                    vt[(((size_t)(hh * 64 + (n >> 5)) * 64 + d) * 32) + (n & 31)] = val;
            }
        }
    }
}

// ---------------- K2: fused attention — 2 waves/block, col-split, pinned pipeline ----------------
// Wave w owns cols w*32 of every 64-col tile. LDS/wave: K 4KB | V 4KB | P 1KB.
__launch_bounds__(128, 4)
__global__ void attn_fused(const unsigned short* __restrict__ qb,
                           const unsigned short* __restrict__ kb,
                           const unsigned short* __restrict__ vt,
                           const float* __restrict__ hist,
                           const float* __restrict__ beta_p,
                           float* __restrict__ attn_out,
                           float* __restrict__ nh_out,
                           float* __restrict__ hv) {
    __shared__ unsigned short SH[2][4608];  // per-wave: K[0..2047] V[2048..4095] P[4096..4607]
    const int tid = threadIdx.x;
    const int w = tid >> 6;
    const int lane = tid & 63;
    const int g = lane >> 4, q15 = lane & 15;
    const int jr = lane >> 3, jc = lane & 7;    // K staging: 8 lanes/row
    const int jrv = lane >> 2, jcv = lane & 3;  // V staging: 4 lanes/row
    const int rb = blockIdx.x, h = blockIdx.y;
    const float beta = beta_p[0];
    const float scale = 0.125f;

    unsigned short* Ksw = SH[w];
    unsigned short* Vsw = SH[w] + 2048;
    unsigned short* Psw = SH[w] + 4096;

    const unsigned short* qsrc = qb + ((size_t)h * N_TOK + rb * 16 + q15) * 64;
    bf16x8 aq0 = *reinterpret_cast<const bf16x8*>(qsrc + 8 * g);
    bf16x8 aq1 = *reinterpret_cast<const bf16x8*>(qsrc + 8 * g + 32);

    const unsigned short* kt0 = kb + (size_t)h * N_TOK * 64 + w * 2048;    // + t*4096
    const unsigned short* vt0 = vt + ((size_t)(h * 64 + w)) * 2048;        // + t*4096
    const float* hbase = hist + ((size_t)h * N_TOK + rb * 16 + q15) * N_TOK + w * 32 + 4 * g;
    float* abase = attn_out + ((size_t)h * N_TOK + rb * 16 + q15) * N_TOK + w * 32 + 4 * g;
    float* nbase = nh_out + ((size_t)h * N_TOK + rb * 16 + q15) * N_TOK + w * 32 + 4 * g;

    float m = -1e30f, l = 0.0f;
    f32x4 h4[2], h4n[2];

    // ---- pass 1 prologue: stage K tile 0 + hist tile 0 ----
    {
        uint4 kr[4];
#pragma unroll
        for (int i = 0; i < 4; i++)
            kr[i] = *reinterpret_cast<const uint4*>(kt0 + (size_t)(i * 8 + jr) * 64 + jc * 8);
#pragma unroll
        for (int i = 0; i < 4; i++) {
            int row = i * 8 + jr;
            *reinterpret_cast<uint4*>(Ksw + row * 64 + ((jc ^ (row & 7)) << 3)) = kr[i];
        }
#pragma unroll
        for (int nt = 0; nt < 2; nt++) h4[nt] = *reinterpret_cast<const f32x4*>(hbase + nt * 16);
    }

    // ---- pass 1: stats ----
    for (int t = 0; t < 32; t++) {
        uint4 kn[4];
        if (t < 31) {
#pragma unroll
            for (int i = 0; i < 4; i++)
                kn[i] = *reinterpret_cast<const uint4*>(kt0 + (size_t)(t + 1) * 4096 + (size_t)(i * 8 + jr) * 64 + jc * 8);
#pragma unroll
            for (int nt = 0; nt < 2; nt++)
                h4n[nt] = *reinterpret_cast<const f32x4*>(hbase + (t + 1) * 64 + nt * 16);
            SB();  // pin prefetch loads here — do not sink
        }
        f32x4 s_acc[2];
#pragma unroll
        for (int nt = 0; nt < 2; nt++) {
            int krow = nt * 16 + q15;
            bf16x8 kf0 = *reinterpret_cast<const bf16x8*>(Ksw + krow * 64 + ((g ^ (q15 & 7)) << 3));
            bf16x8 kf1 = *reinterpret_cast<const bf16x8*>(Ksw + krow * 64 + (((4 + g) ^ (q15 & 7)) << 3));
            s_acc[nt] = __builtin_amdgcn_mfma_f32_16x16x32_bf16(kf0, aq0, zero4(), 0, 0, 0);
            s_acc[nt] = __builtin_amdgcn_mfma_f32_16x16x32_bf16(kf1, aq1, s_acc[nt], 0, 0, 0);
        }
        float sc[2][4];
#pragma unroll
        for (int nt = 0; nt < 2; nt++)
#pragma unroll
            for (int r = 0; r < 4; r++)
                sc[nt][r] = s_acc[nt][r] * scale + beta * h4[nt][r];

        float tm = sc[0][0];
#pragma unroll
        for (int nt = 0; nt < 2; nt++)
#pragma unroll
            for (int r = 0; r < 4; r++) tm = fmaxf(tm, sc[nt][r]);
        tm = fmaxf(tm, __shfl_xor(tm, 16));
        tm = fmaxf(tm, __shfl_xor(tm, 32));
        float mn = fmaxf(m, tm);
        float ps = 0.0f;
#pragma unroll
        for (int nt = 0; nt < 2; nt++)
#pragma unroll
            for (int r = 0; r < 4; r++) ps += __expf(sc[nt][r] - mn);
        ps += __shfl_xor(ps, 16);
        ps += __shfl_xor(ps, 32);
        l = l * __expf(m - mn) + ps;
        m = mn;

        if (t < 31) {
            SB();
            asm volatile("s_waitcnt vmcnt(0)" ::: "memory");
            SB();
#pragma unroll
            for (int i = 0; i < 4; i++) {
                int row = i * 8 + jr;
                *reinterpret_cast<uint4*>(Ksw + row * 64 + ((jc ^ (row & 7)) << 3)) = kn[i];
            }
#pragma unroll
            for (int nt = 0; nt < 2; nt++) h4[nt] = h4n[nt];
        }
    }

    // ---- cross-wave stats merge (barriers 1 & 2) ----
    float inv_l;
    {
        float* mlbuf = (float*)(SH[0] + 4096);  // overlay wave-0 P region (unused until pass 2)
        if (g == 0) {
            mlbuf[w * 16 + q15] = m;
            mlbuf[32 + w * 16 + q15] = l;
        }
        __syncthreads();
        float m0 = mlbuf[q15], m1 = mlbuf[16 + q15];
        float l0 = mlbuf[32 + q15], l1 = mlbuf[48 + q15];
        float gm = fmaxf(m0, m1);
        float gl = l0 * __expf(m0 - gm) + l1 * __expf(m1 - gm);
        m = gm;
        inv_l = 1.0f / gl;
        __syncthreads();  // protect mlbuf before P region reuse
    }

    f32x4 oacc[4];
#pragma unroll
    for (int di = 0; di < 4; di++) oacc[di] = zero4();

    // ---- pass 2 prologue: K tile 31 still staged; stage V tile 31 + hist tile 31 ----
    {
        uint4 vr[4];
#pragma unroll
        for (int i = 0; i < 4; i++)
            vr[i] = *reinterpret_cast<const uint4*>(vt0 + (size_t)31 * 4096 + (size_t)(i * 16 + jrv) * 32 + jcv * 8);
#pragma unroll
        for (int i = 0; i < 4; i++) {
            int row = i * 16 + jrv;
            *reinterpret_cast<uint4*>(Vsw + row * 32 + ((jcv ^ ((row >> 1) & 3)) << 3)) = vr[i];
        }
#pragma unroll
        for (int nt = 0; nt < 2; nt++)
            h4[nt] = *reinterpret_cast<const f32x4*>(hbase + 31 * 64 + nt * 16);
    }

    // ---- pass 2: emit attn/nh + PV (reverse order for L2/L3 hist reuse) ----
    for (int tt = 0; tt < 32; tt++) {
        const int t = 31 - tt;
        uint4 kn[4], vn[4];
        if (tt < 31) {
#pragma unroll
            for (int i = 0; i < 4; i++) {
                kn[i] = *reinterpret_cast<const uint4*>(kt0 + (size_t)(t - 1) * 4096 + (size_t)(i * 8 + jr) * 64 + jc * 8);
                vn[i] = *reinterpret_cast<const uint4*>(vt0 + (size_t)(t - 1) * 4096 + (size_t)(i * 16 + jrv) * 32 + jcv * 8);
            }
#pragma unroll
            for (int nt = 0; nt < 2; nt++)
                h4n[nt] = *reinterpret_cast<const f32x4*>(hbase + (t - 1) * 64 + nt * 16);
            SB();  // pin prefetch loads here
        }

        f32x4 s_acc[2];
#pragma unroll
        for (int nt = 0; nt < 2; nt++) {
            int krow = nt * 16 + q15;
            bf16x8 kf0 = *reinterpret_cast<const bf16x8*>(Ksw + krow * 64 + ((g ^ (q15 & 7)) << 3));
            bf16x8 kf1 = *reinterpret_cast<const bf16x8*>(Ksw + krow * 64 + (((4 + g) ^ (q15 & 7)) << 3));
            s_acc[nt] = __builtin_amdgcn_mfma_f32_16x16x32_bf16(kf0, aq0, zero4(), 0, 0, 0);
            s_acc[nt] = __builtin_amdgcn_mfma_f32_16x16x32_bf16(kf1, aq1, s_acc[nt], 0, 0, 0);
        }

#pragma unroll
        for (int nt = 0; nt < 2; nt++) {
            float a0 = __expf(s_acc[nt][0] * scale + beta * h4[nt][0] - m) * inv_l;
            float a1 = __expf(s_acc[nt][1] * scale + beta * h4[nt][1] - m) * inv_l;
            float a2 = __expf(s_acc[nt][2] * scale + beta * h4[nt][2] - m) * inv_l;
            float a3 = __expf(s_acc[nt][3] * scale + beta * h4[nt][3] - m) * inv_l;
            f32x4 av, nv;
            av[0] = a0; av[1] = a1; av[2] = a2; av[3] = a3;
            nv[0] = a0 + h4[nt][0]; nv[1] = a1 + h4[nt][1];
            nv[2] = a2 + h4[nt][2]; nv[3] = a3 + h4[nt][3];
            __builtin_nontemporal_store(av, reinterpret_cast<f32x4*>(abase + t * 64 + nt * 16));
            __builtin_nontemporal_store(nv, reinterpret_cast<f32x4*>(nbase + t * 64 + nt * 16));
            ushort4 p;
            p.x = f2bf(a0); p.y = f2bf(a1); p.z = f2bf(a2); p.w = f2bf(a3);
            *reinterpret_cast<ushort4*>(Psw + q15 * 32 + (((4 * nt + g) ^ (q15 & 6)) << 2)) = p;
        }

        {
            bf16x8 pa = *reinterpret_cast<const bf16x8*>(Psw + q15 * 32 + (((2 * g) ^ (q15 & 6)) << 2));
#pragma unroll
            for (int di = 0; di < 4; di++) {
                int vrow = di * 16 + q15;
                bf16x8 vf = *reinterpret_cast<const bf16x8*>(Vsw + vrow * 32 + ((g ^ ((q15 >> 1) & 3)) << 3));
                oacc[di] = __builtin_amdgcn_mfma_f32_16x16x32_bf16(pa, vf, oacc[di], 0, 0, 0);
            }
        }

        if (tt < 31) {
            SB();
            // wait prefetch loads; leave this iteration's 4 NT stores in flight
            asm volatile("s_waitcnt vmcnt(4)" ::: "memory");
            SB();
#pragma unroll
            for (int i = 0; i < 4; i++) {
                int row = i * 8 + jr;
                *reinterpret_cast<uint4*>(Ksw + row * 64 + ((jc ^ (row & 7)) << 3)) = kn[i];
            }
#pragma unroll
            for (int i = 0; i < 4; i++) {
                int row = i * 16 + jrv;
                *reinterpret_cast<uint4*>(Vsw + row * 32 + ((jcv ^ ((row >> 1) & 3)) << 3)) = vn[i];
            }
#pragma unroll
            for (int nt = 0; nt < 2; nt++) h4[nt] = h4n[nt];
        }
    }

    // ---- cross-wave PV merge (barrier 3) + hv write ----
    {
        float* vbuf = (float*)(SH[1] + 2048);  // overlay wave-1 V region (done with V)
        if (w == 1) {
#pragma unroll
            for (int di = 0; di < 4; di++)
#pragma unroll
                for (int r = 0; r < 4; r++)
                    vbuf[(4 * g + r) * 64 + di * 16 + q15] = oacc[di][r];
        }
        __syncthreads();
        if (w == 0) {
#pragma unroll
            for (int di = 0; di < 4; di++) {
#pragma unroll
                for (int r = 0; r < 4; r++) {
                    int rl = 4 * g + r;
                    int d = di * 16 + q15;
                    hv[((size_t)h * N_TOK + rb * 16 + rl) * 64 + d] =
                        oacc[di][r] + vbuf[rl * 64 + d];
                }
            }
        }
    }
}

// ---------------- K3: output projection ----------------
__launch_bounds__(256)
__global__ void out_proj(const float* __restrict__ hv, const float* __restrict__ Wo,
                         const float* __restrict__ bo, float* __restrict__ out) {
    __shared__ float wos[64][129];
    const int tid = threadIdx.x;
    const int dd = tid & 63;
    const int w = tid >> 6;
    const int n0 = blockIdx.x * 16;
    float acc[4] = {0.f, 0.f, 0.f, 0.f};
    for (int kc = 0; kc < 1024; kc += 128) {
        __syncthreads();
#pragma unroll
        for (int i = 0; i < 32; i++) {
            int e = tid + 256 * i;
            int r = e >> 7, j = e & 127;
            wos[r][j] = Wo[(size_t)r * 1024 + kc + j];
        }
        __syncthreads();
#pragma unroll 4
        for (int k = 0; k < 128; k++) {
            float wv = wos[dd][k];
            int jg = kc + k;
            const float* hb = hv + ((size_t)(jg >> 6) * N_TOK) * 64 + (jg & 63);
#pragma unroll
            for (int q = 0; q < 4; q++) {
                acc[q] += hb[(size_t)(n0 + w + 4 * q) * 64] * wv;
            }
        }
    }
#pragma unroll
    for (int q = 0; q < 4; q++)
        out[(size_t)(n0 + w + 4 * q) * 64 + dd] = acc[q] + bo[dd];
}

extern "C" void kernel_launch(void* const* d_in, const int* in_sizes, int n_in,
                              void* d_out, int out_size, void* d_ws, size_t ws_size,
                              hipStream_t stream) {
    const float* x    = (const float*)d_in[0];
    const float* hist = (const float*)d_in[1];
    const float* Wq_w = (const float*)d_in[2];
    const float* Wq_b = (const float*)d_in[3];
    const float* Wk_w = (const float*)d_in[4];
    const float* Wk_b = (const float*)d_in[5];
    const float* Wv_w = (const float*)d_in[6];
    const float* Wv_b = (const float*)d_in[7];
    const float* Wo_w = (const float*)d_in[8];
    const float* Wo_b = (const float*)d_in[9];
    const float* beta = (const float*)d_in[10];

    float* out = (float*)d_out;
    float* attn_out = out + 131072;
    float* nh_out = attn_out + (size_t)NHEAD * N_TOK * N_TOK;

    unsigned short* xb  = (unsigned short*)d_ws;                 // 2M shorts
    unsigned short* wb  = xb + (size_t)N_TOK * HIDDEN;           // 3M shorts
    unsigned short* qb  = wb + (size_t)3 * HIDDEN * HIDDEN;      // 2M
    unsigned short* kb  = qb + (size_t)N_TOK * HIDDEN;
    unsigned short* vt  = kb + (size_t)N_TOK * HIDDEN;
    float* hvb = (float*)(vt + (size_t)N_TOK * HIDDEN);          // 2M f32

    cvt4_kernel<<<5120, 256, 0, stream>>>(x, Wq_w, Wk_w, Wv_w, xb);
    gemm_qkv<<<dim3(24, 16), 256, 0, stream>>>(xb, wb, Wq_b, Wk_b, Wv_b, qb, kb, vt);
    attn_fused<<<dim3(128, 16), 128, 0, stream>>>(qb, kb, vt, hist, beta,
                                                  attn_out, nh_out, hvb);
    out_proj<<<128, 256, 0, stream>>>(hvb, Wo_w, Wo_b, out);
}

// Round 9
// 520.729 us; speedup vs baseline: 1.0732x; 1.0732x over previous
//
#include <hip/hip_runtime.h>
#include <hip/hip_bf16.h>

#define N_TOK 2048
#define HIDDEN 1024
#define NHEAD 16
#define DHEAD 64

typedef __attribute__((ext_vector_type(8))) short bf16x8;
typedef __attribute__((ext_vector_type(4))) float f32x4;

#define WAITV(N) do { asm volatile("s_waitcnt vmcnt(" #N ")" ::: "memory"); \
                      __builtin_amdgcn_sched_barrier(0); } while (0)

__device__ inline unsigned short f2bf(float x) {
    __hip_bfloat16 h = __float2bfloat16(x);
    return *reinterpret_cast<unsigned short*>(&h);
}

__device__ inline f32x4 zero4() {
    f32x4 z;
    z[0] = 0.f; z[1] = 0.f; z[2] = 0.f; z[3] = 0.f;
    return z;
}

// async global->LDS, 16B per lane; dest = uniform base + lane*16
__device__ inline void gl_lds16(const unsigned short* g, unsigned short* l) {
    __builtin_amdgcn_global_load_lds(
        (const __attribute__((address_space(1))) unsigned int*)g,
        (__attribute__((address_space(3))) unsigned int*)l, 16, 0, 0);
}

// ---------------- K0: fused f32 -> bf16 conversion for x, Wq, Wk, Wv ----------------
__global__ void cvt4_kernel(const float* __restrict__ x, const float* __restrict__ wq,
                            const float* __restrict__ wk, const float* __restrict__ wv,
                            unsigned short* __restrict__ dst) {
    int i = blockIdx.x * blockDim.x + threadIdx.x;  // 1310720 float4 jobs
    const float* src;
    int off;
    if (i < 524288)       { src = x;  off = i; }
    else if (i < 786432)  { src = wq; off = i - 524288; }
    else if (i < 1048576) { src = wk; off = i - 786432; }
    else                  { src = wv; off = i - 1048576; }
    float4 v = reinterpret_cast<const float4*>(src)[off];
    ushort4 o;
    o.x = f2bf(v.x); o.y = f2bf(v.y); o.z = f2bf(v.z); o.w = f2bf(v.w);
    reinterpret_cast<ushort4*>(dst)[i] = o;
}

// ---------------- K1: fused QKV GEMM; v-region writes tiled vt directly ----------------
__launch_bounds__(256)
__global__ void gemm_qkv(const unsigned short* __restrict__ xb,
                         const unsigned short* __restrict__ wb,
                         const float* __restrict__ bq, const float* __restrict__ bk,
                         const float* __restrict__ bv,
                         unsigned short* __restrict__ qb, unsigned short* __restrict__ kb,
                         unsigned short* __restrict__ vt) {
    __shared__ unsigned short As[2][128 * 64];
    __shared__ unsigned short Bs[2][128 * 64];
    const int tid = threadIdx.x;
    const int lane = tid & 63;
    const int w = tid >> 6;
    const int wr = w >> 1, wc = w & 1;
    const int rb = blockIdx.y * 128;
    const int cb = blockIdx.x * 128;
    const int r0 = tid >> 3, c0 = tid & 7;

    f32x4 acc[4][4];
    for (int i = 0; i < 4; i++)
        for (int j = 0; j < 4; j++) acc[i][j] = zero4();

    uint4 va[4], vb4[4];
#pragma unroll
    for (int i = 0; i < 4; i++) {
        va[i]  = *reinterpret_cast<const uint4*>(xb + (size_t)(rb + r0 + 32 * i) * HIDDEN + c0 * 8);
        vb4[i] = *reinterpret_cast<const uint4*>(wb + (size_t)(cb + r0 + 32 * i) * HIDDEN + c0 * 8);
    }
#pragma unroll
    for (int i = 0; i < 4; i++) {
        int row = r0 + 32 * i;
        *reinterpret_cast<uint4*>(As[0] + row * 64 + ((c0 ^ (row & 7)) << 3)) = va[i];
        *reinterpret_cast<uint4*>(Bs[0] + row * 64 + ((c0 ^ (row & 7)) << 3)) = vb4[i];
    }
    __syncthreads();
    int cur = 0;

    for (int kt = 0; kt < 16; ++kt) {
        if (kt < 15) {
#pragma unroll
            for (int i = 0; i < 4; i++) {
                va[i]  = *reinterpret_cast<const uint4*>(xb + (size_t)(rb + r0 + 32 * i) * HIDDEN + (kt + 1) * 64 + c0 * 8);
                vb4[i] = *reinterpret_cast<const uint4*>(wb + (size_t)(cb + r0 + 32 * i) * HIDDEN + (kt + 1) * 64 + c0 * 8);
            }
        }
#pragma unroll
        for (int kk = 0; kk < 2; kk++) {
            bf16x8 a[4], b[4];
#pragma unroll
            for (int mi = 0; mi < 4; mi++) {
                int row = wr * 64 + mi * 16 + (lane & 15);
                a[mi] = *reinterpret_cast<const bf16x8*>(As[cur] + row * 64 + (((kk * 4 + (lane >> 4)) ^ (row & 7)) << 3));
            }
#pragma unroll
            for (int ni = 0; ni < 4; ni++) {
                int row = wc * 64 + ni * 16 + (lane & 15);
                b[ni] = *reinterpret_cast<const bf16x8*>(Bs[cur] + row * 64 + (((kk * 4 + (lane >> 4)) ^ (row & 7)) << 3));
            }
#pragma unroll
            for (int mi = 0; mi < 4; mi++)
#pragma unroll
                for (int ni = 0; ni < 4; ni++)
                    acc[mi][ni] = __builtin_amdgcn_mfma_f32_16x16x32_bf16(a[mi], b[ni], acc[mi][ni], 0, 0, 0);
        }
        if (kt < 15) {
#pragma unroll
            for (int i = 0; i < 4; i++) {
                int row = r0 + 32 * i;
                *reinterpret_cast<uint4*>(As[cur ^ 1] + row * 64 + ((c0 ^ (row & 7)) << 3)) = va[i];
                *reinterpret_cast<uint4*>(Bs[cur ^ 1] + row * 64 + ((c0 ^ (row & 7)) << 3)) = vb4[i];
            }
        }
        __syncthreads();
        cur ^= 1;
    }

    const int region = blockIdx.x >> 3;  // 0=q, 1=k, 2=v
    const float* bias = region == 0 ? bq : (region == 1 ? bk : bv);
    unsigned short* dst = region == 0 ? qb : kb;
#pragma unroll
    for (int mi = 0; mi < 4; mi++) {
#pragma unroll
        for (int ni = 0; ni < 4; ni++) {
            int colg = cb + wc * 64 + ni * 16 + (lane & 15);
            int jj = colg & 1023;
            int hh = jj >> 6, d = jj & 63;
            float bval = bias[jj];
#pragma unroll
            for (int r = 0; r < 4; r++) {
                int n = rb + wr * 64 + mi * 16 + ((lane >> 4) << 2) + r;
                unsigned short val = f2bf(acc[mi][ni][r] + bval);
                if (region < 2)
                    dst[((size_t)hh * N_TOK + n) * 64 + d] = val;
                else  // v: tiled layout vt[((h*64 + n/32)*64 + d)*32 + n%32]
                    vt[(((size_t)(hh * 64 + (n >> 5)) * 64 + d) * 32) + (n & 31)] = val;
            }
        }
    }
}

// ---------------- K2: fused attention — 1 wave/block, global_load_lds dbuf, counted vmcnt ----------------
// 32-col tiles, 64 tiles, two passes. LDS: K 2x4KB | V 2x4KB | P 1KB = 17KB -> 9 blocks/CU.
__launch_bounds__(64, 2)
__global__ void attn_fused(const unsigned short* __restrict__ qb,
                           const unsigned short* __restrict__ kb,
                           const unsigned short* __restrict__ vt,
                           const float* __restrict__ hist,
                           const float* __restrict__ beta_p,
                           float* __restrict__ attn_out,
                           float* __restrict__ nh_out,
                           float* __restrict__ hv) {
    __shared__ unsigned short Kbuf[2][2048];
    __shared__ unsigned short Vbuf[2][2048];
    __shared__ unsigned short Psw[512];
    const int lane = threadIdx.x;
    const int g = lane >> 4, q15 = lane & 15;
    // XCD swizzle: each XCD gets 2 consecutive heads (K/V working set 1MB < 4MB L2)
    const int bid = blockIdx.x;
    const int orig = (bid & 7) * 256 + (bid >> 3);
    const int h = orig >> 7, rb = orig & 127;
    const float beta = beta_p[0];
    const float scale = 0.125f;

    const unsigned short* qsrc = qb + ((size_t)h * N_TOK + rb * 16 + q15) * 64;
    bf16x8 aq0 = *reinterpret_cast<const bf16x8*>(qsrc + 8 * g);
    bf16x8 aq1 = *reinterpret_cast<const bf16x8*>(qsrc + 8 * g + 32);

    // staging: linear LDS dest; inverse-swizzled per-lane SOURCE (rule #21)
    // K tile [32 rows][128B]: slot(16B) xor (row&7);  V tile [64 rows][64B]: slot xor ((row>>1)&3)
    const int koff = (lane >> 3) * 64 + (((lane & 7) ^ (lane >> 3)) << 3);          // shorts
    const int voff = (lane >> 2) * 32 + (((lane & 3) ^ ((lane >> 3) & 3)) << 3);    // shorts
    const unsigned short* kt0 = kb + (size_t)h * N_TOK * 64;  // + t*2048
    const unsigned short* vt0 = vt + (size_t)h * N_TOK * 64;  // + t*2048 (pre-tiled [t][d][32])

#define STAGE_K(T, B) do { const unsigned short* _s = kt0 + (size_t)(T) * 2048 + koff; \
        gl_lds16(_s,        &Kbuf[B][0]);    gl_lds16(_s + 512,  &Kbuf[B][512]);   \
        gl_lds16(_s + 1024, &Kbuf[B][1024]); gl_lds16(_s + 1536, &Kbuf[B][1536]); } while (0)
#define STAGE_V(T, B) do { const unsigned short* _s = vt0 + (size_t)(T) * 2048 + voff; \
        gl_lds16(_s,        &Vbuf[B][0]);    gl_lds16(_s + 512,  &Vbuf[B][512]);   \
        gl_lds16(_s + 1024, &Vbuf[B][1024]); gl_lds16(_s + 1536, &Vbuf[B][1536]); } while (0)

    const size_t rowbase = ((size_t)h * N_TOK + rb * 16 + q15) * N_TOK;
    const float* hbase = hist + rowbase + 4 * g;
    float* abase = attn_out + rowbase + 4 * g;
    float* nbase = nh_out + rowbase + 4 * g;

    float m = -1e30f, l = 0.0f;
    f32x4 h4[2], h4n[2];

    // ---- pass 1 prologue ----
    STAGE_K(0, 0);
    h4[0] = *reinterpret_cast<const f32x4*>(hbase);
    h4[1] = *reinterpret_cast<const f32x4*>(hbase + 16);

    // ---- pass 1: stats ----
    for (int t = 0; t < 64; ++t) {
        const int cur = t & 1;
        if (t < 63) {
            STAGE_K(t + 1, cur ^ 1);
            h4n[0] = *reinterpret_cast<const f32x4*>(hbase + (t + 1) * 32);
            h4n[1] = *reinterpret_cast<const f32x4*>(hbase + (t + 1) * 32 + 16);
            WAITV(6);   // retire stage(t)+hist(t); leave stage(t+1)4 + hist(t+1)2 in flight
        } else {
            WAITV(0);
        }
        f32x4 s_acc[2];
#pragma unroll
        for (int nt = 0; nt < 2; ++nt) {
            int krow = nt * 16 + q15;
            bf16x8 kf0 = *reinterpret_cast<const bf16x8*>(Kbuf[cur] + krow * 64 + ((g ^ (q15 & 7)) << 3));
            bf16x8 kf1 = *reinterpret_cast<const bf16x8*>(Kbuf[cur] + krow * 64 + (((4 + g) ^ (q15 & 7)) << 3));
            s_acc[nt] = __builtin_amdgcn_mfma_f32_16x16x32_bf16(kf0, aq0, zero4(), 0, 0, 0);
            s_acc[nt] = __builtin_amdgcn_mfma_f32_16x16x32_bf16(kf1, aq1, s_acc[nt], 0, 0, 0);
        }
        float sc[2][4];
#pragma unroll
        for (int nt = 0; nt < 2; ++nt)
#pragma unroll
            for (int r = 0; r < 4; ++r)
                sc[nt][r] = s_acc[nt][r] * scale + beta * h4[nt][r];

        float tm = sc[0][0];
#pragma unroll
        for (int nt = 0; nt < 2; ++nt)
#pragma unroll
            for (int r = 0; r < 4; ++r) tm = fmaxf(tm, sc[nt][r]);
        tm = fmaxf(tm, __shfl_xor(tm, 16));
        tm = fmaxf(tm, __shfl_xor(tm, 32));
        float mn = fmaxf(m, tm);
        float ps = 0.0f;
#pragma unroll
        for (int nt = 0; nt < 2; ++nt)
#pragma unroll
            for (int r = 0; r < 4; ++r) ps += __expf(sc[nt][r] - mn);
        ps += __shfl_xor(ps, 16);
        ps += __shfl_xor(ps, 32);
        l = l * __expf(m - mn) + ps;
        m = mn;

        h4[0] = h4n[0]; h4[1] = h4n[1];
    }
    const float inv_l = 1.0f / l;

    f32x4 oacc[4];
#pragma unroll
    for (int di = 0; di < 4; ++di) oacc[di] = zero4();

    // ---- pass 2 prologue: K(63) still resident in Kbuf[1]; stage V(63)->Vbuf[1] ----
    STAGE_V(63, 1);
    h4[0] = *reinterpret_cast<const f32x4*>(hbase + 63 * 32);
    h4[1] = *reinterpret_cast<const f32x4*>(hbase + 63 * 32 + 16);

    f32x4 sa0, sa1, sn0, sn1;  // deferred NT-store payload (tile t+1)

    // ---- pass 2: emit attn/nh + PV (reverse order for L2/L3 hist reuse) ----
    for (int tt = 0; tt < 64; ++tt) {
        const int t = 63 - tt;
        const int cur = t & 1;
        if (tt > 0) {  // deferred stores of tile t+1 — newest in vmcnt queue, never force-drained
            __builtin_nontemporal_store(sa0, reinterpret_cast<f32x4*>(abase + (t + 1) * 32));
            __builtin_nontemporal_store(sa1, reinterpret_cast<f32x4*>(abase + (t + 1) * 32 + 16));
            __builtin_nontemporal_store(sn0, reinterpret_cast<f32x4*>(nbase + (t + 1) * 32));
            __builtin_nontemporal_store(sn1, reinterpret_cast<f32x4*>(nbase + (t + 1) * 32 + 16));
        }
        if (tt < 63) {
            STAGE_K(t - 1, cur ^ 1);
            STAGE_V(t - 1, cur ^ 1);
            h4n[0] = *reinterpret_cast<const f32x4*>(hbase + (t - 1) * 32);
            h4n[1] = *reinterpret_cast<const f32x4*>(hbase + (t - 1) * 32 + 16);
        }
        if (tt == 0)      { WAITV(10); }
        else if (tt < 63) { WAITV(14); }   // retire stage(t)+hist(t)+old stores; keep 14 newest in flight
        else              { WAITV(4);  }

        f32x4 s_acc[2];
#pragma unroll
        for (int nt = 0; nt < 2; ++nt) {
            int krow = nt * 16 + q15;
            bf16x8 kf0 = *reinterpret_cast<const bf16x8*>(Kbuf[cur] + krow * 64 + ((g ^ (q15 & 7)) << 3));
            bf16x8 kf1 = *reinterpret_cast<const bf16x8*>(Kbuf[cur] + krow * 64 + (((4 + g) ^ (q15 & 7)) << 3));
            s_acc[nt] = __builtin_amdgcn_mfma_f32_16x16x32_bf16(kf0, aq0, zero4(), 0, 0, 0);
            s_acc[nt] = __builtin_amdgcn_mfma_f32_16x16x32_bf16(kf1, aq1, s_acc[nt], 0, 0, 0);
        }

#pragma unroll
        for (int nt = 0; nt < 2; ++nt) {
            float a0 = __expf(s_acc[nt][0] * scale + beta * h4[nt][0] - m) * inv_l;
            float a1 = __expf(s_acc[nt][1] * scale + beta * h4[nt][1] - m) * inv_l;
            float a2 = __expf(s_acc[nt][2] * scale + beta * h4[nt][2] - m) * inv_l;
            float a3 = __expf(s_acc[nt][3] * scale + beta * h4[nt][3] - m) * inv_l;
            f32x4 av, nv;
            av[0] = a0; av[1] = a1; av[2] = a2; av[3] = a3;
            nv[0] = a0 + h4[nt][0]; nv[1] = a1 + h4[nt][1];
            nv[2] = a2 + h4[nt][2]; nv[3] = a3 + h4[nt][3];
            if (nt == 0) { sa0 = av; sn0 = nv; } else { sa1 = av; sn1 = nv; }
            ushort4 p;
            p.x = f2bf(a0); p.y = f2bf(a1); p.z = f2bf(a2); p.w = f2bf(a3);
            *reinterpret_cast<ushort4*>(Psw + q15 * 32 + (((4 * nt + g) ^ (q15 & 6)) << 2)) = p;
        }

        {
            bf16x8 pa = *reinterpret_cast<const bf16x8*>(Psw + q15 * 32 + (((2 * g) ^ (q15 & 6)) << 2));
#pragma unroll
            for (int di = 0; di < 4; ++di) {
                int vrow = di * 16 + q15;
                bf16x8 vf = *reinterpret_cast<const bf16x8*>(Vbuf[cur] + vrow * 32 + ((g ^ ((q15 >> 1) & 3)) << 3));
                oacc[di] = __builtin_amdgcn_mfma_f32_16x16x32_bf16(pa, vf, oacc[di], 0, 0, 0);
            }
        }

        h4[0] = h4n[0]; h4[1] = h4n[1];
    }
    // final stores of tile 0
    __builtin_nontemporal_store(sa0, reinterpret_cast<f32x4*>(abase));
    __builtin_nontemporal_store(sa1, reinterpret_cast<f32x4*>(abase + 16));
    __builtin_nontemporal_store(sn0, reinterpret_cast<f32x4*>(nbase));
    __builtin_nontemporal_store(sn1, reinterpret_cast<f32x4*>(nbase + 16));

    // epilogue: hv write (complete over all cols)
#pragma unroll
    for (int di = 0; di < 4; ++di) {
#pragma unroll
        for (int r = 0; r < 4; ++r) {
            int rl = g * 4 + r;
            int d = di * 16 + q15;
            hv[((size_t)h * N_TOK + rb * 16 + rl) * 64 + d] = oacc[di][r];
        }
    }
#undef STAGE_K
#undef STAGE_V
}

// ---------------- K3: output projection ----------------
__launch_bounds__(256)
__global__ void out_proj(const float* __restrict__ hv, const float* __restrict__ Wo,
                         const float* __restrict__ bo, float* __restrict__ out) {
    __shared__ float wos[64][129];
    const int tid = threadIdx.x;
    const int dd = tid & 63;
    const int w = tid >> 6;
    const int n0 = blockIdx.x * 16;
    float acc[4] = {0.f, 0.f, 0.f, 0.f};
    for (int kc = 0; kc < 1024; kc += 128) {
        __syncthreads();
#pragma unroll
        for (int i = 0; i < 32; i++) {
            int e = tid + 256 * i;
            int r = e >> 7, j = e & 127;
            wos[r][j] = Wo[(size_t)r * 1024 + kc + j];
        }
        __syncthreads();
#pragma unroll 4
        for (int k = 0; k < 128; k++) {
            float wv = wos[dd][k];
            int jg = kc + k;
            const float* hb = hv + ((size_t)(jg >> 6) * N_TOK) * 64 + (jg & 63);
#pragma unroll
            for (int q = 0; q < 4; q++) {
                acc[q] += hb[(size_t)(n0 + w + 4 * q) * 64] * wv;
            }
        }
    }
#pragma unroll
    for (int q = 0; q < 4; q++)
        out[(size_t)(n0 + w + 4 * q) * 64 + dd] = acc[q] + bo[dd];
}

extern "C" void kernel_launch(void* const* d_in, const int* in_sizes, int n_in,
                              void* d_out, int out_size, void* d_ws, size_t ws_size,
                              hipStream_t stream) {
    const float* x    = (const float*)d_in[0];
    const float* hist = (const float*)d_in[1];
    const float* Wq_w = (const float*)d_in[2];
    const float* Wq_b = (const float*)d_in[3];
    const float* Wk_w = (const float*)d_in[4];
    const float* Wk_b = (const float*)d_in[5];
    const float* Wv_w = (const float*)d_in[6];
    const float* Wv_b = (const float*)d_in[7];
    const float* Wo_w = (const float*)d_in[8];
    const float* Wo_b = (const float*)d_in[9];
    const float* beta = (const float*)d_in[10];

    float* out = (float*)d_out;
    float* attn_out = out + 131072;
    float* nh_out = attn_out + (size_t)NHEAD * N_TOK * N_TOK;

    unsigned short* xb  = (unsigned short*)d_ws;                 // 2M shorts
    unsigned short* wb  = xb + (size_t)N_TOK * HIDDEN;           // 3M shorts
    unsigned short* qb  = wb + (size_t)3 * HIDDEN * HIDDEN;      // 2M
    unsigned short* kb  = qb + (size_t)N_TOK * HIDDEN;
    unsigned short* vt  = kb + (size_t)N_TOK * HIDDEN;
    float* hvb = (float*)(vt + (size_t)N_TOK * HIDDEN);          // 2M f32

    cvt4_kernel<<<5120, 256, 0, stream>>>(x, Wq_w, Wk_w, Wv_w, xb);
    gemm_qkv<<<dim3(24, 16), 256, 0, stream>>>(xb, wb, Wq_b, Wk_b, Wv_b, qb, kb, vt);
    attn_fused<<<2048, 64, 0, stream>>>(qb, kb, vt, hist, beta, attn_out, nh_out, hvb);
    out_proj<<<128, 256, 0, stream>>>(hvb, Wo_w, Wo_b, out);
}

// Round 10
// 520.488 us; speedup vs baseline: 1.0737x; 1.0005x over previous
//
#include <hip/hip_runtime.h>
#include <hip/hip_bf16.h>

#define N_TOK 2048
#define HIDDEN 1024
#define NHEAD 16
#define DHEAD 64

typedef __attribute__((ext_vector_type(8))) short bf16x8;
typedef __attribute__((ext_vector_type(4))) float f32x4;

#define WAITV(N) do { asm volatile("s_waitcnt vmcnt(" #N ")" ::: "memory"); \
                      __builtin_amdgcn_sched_barrier(0); } while (0)

__device__ inline unsigned short f2bf(float x) {
    __hip_bfloat16 h = __float2bfloat16(x);
    return *reinterpret_cast<unsigned short*>(&h);
}

__device__ inline f32x4 zero4() {
    f32x4 z;
    z[0] = 0.f; z[1] = 0.f; z[2] = 0.f; z[3] = 0.f;
    return z;
}

// async global->LDS, 16B per lane; dest = uniform base + lane*16
__device__ inline void gl_lds16(const unsigned short* g, unsigned short* l) {
    __builtin_amdgcn_global_load_lds(
        (const __attribute__((address_space(1))) unsigned int*)g,
        (__attribute__((address_space(3))) unsigned int*)l, 16, 0, 0);
}

// ---------------- K0: fused f32 -> bf16 conversion for x, Wq, Wk, Wv ----------------
__global__ void cvt4_kernel(const float* __restrict__ x, const float* __restrict__ wq,
                            const float* __restrict__ wk, const float* __restrict__ wv,
                            unsigned short* __restrict__ dst) {
    int i = blockIdx.x * blockDim.x + threadIdx.x;  // 1310720 float4 jobs
    const float* src;
    int off;
    if (i < 524288)       { src = x;  off = i; }
    else if (i < 786432)  { src = wq; off = i - 524288; }
    else if (i < 1048576) { src = wk; off = i - 786432; }
    else                  { src = wv; off = i - 1048576; }
    float4 v = reinterpret_cast<const float4*>(src)[off];
    ushort4 o;
    o.x = f2bf(v.x); o.y = f2bf(v.y); o.z = f2bf(v.z); o.w = f2bf(v.w);
    reinterpret_cast<ushort4*>(dst)[i] = o;
}

// ---------------- K1: fused QKV GEMM; v-region writes tiled vt directly ----------------
__launch_bounds__(256)
__global__ void gemm_qkv(const unsigned short* __restrict__ xb,
                         const unsigned short* __restrict__ wb,
                         const float* __restrict__ bq, const float* __restrict__ bk,
                         const float* __restrict__ bv,
                         unsigned short* __restrict__ qb, unsigned short* __restrict__ kb,
                         unsigned short* __restrict__ vt) {
    __shared__ unsigned short As[2][128 * 64];
    __shared__ unsigned short Bs[2][128 * 64];
    const int tid = threadIdx.x;
    const int lane = tid & 63;
    const int w = tid >> 6;
    const int wr = w >> 1, wc = w & 1;
    const int rb = blockIdx.y * 128;
    const int cb = blockIdx.x * 128;
    const int r0 = tid >> 3, c0 = tid & 7;

    f32x4 acc[4][4];
    for (int i = 0; i < 4; i++)
        for (int j = 0; j < 4; j++) acc[i][j] = zero4();

    uint4 va[4], vb4[4];
#pragma unroll
    for (int i = 0; i < 4; i++) {
        va[i]  = *reinterpret_cast<const uint4*>(xb + (size_t)(rb + r0 + 32 * i) * HIDDEN + c0 * 8);
        vb4[i] = *reinterpret_cast<const uint4*>(wb + (size_t)(cb + r0 + 32 * i) * HIDDEN + c0 * 8);
    }
#pragma unroll
    for (int i = 0; i < 4; i++) {
        int row = r0 + 32 * i;
        *reinterpret_cast<uint4*>(As[0] + row * 64 + ((c0 ^ (row & 7)) << 3)) = va[i];
        *reinterpret_cast<uint4*>(Bs[0] + row * 64 + ((c0 ^ (row & 7)) << 3)) = vb4[i];
    }
    __syncthreads();
    int cur = 0;

    for (int kt = 0; kt < 16; ++kt) {
        if (kt < 15) {
#pragma unroll
            for (int i = 0; i < 4; i++) {
                va[i]  = *reinterpret_cast<const uint4*>(xb + (size_t)(rb + r0 + 32 * i) * HIDDEN + (kt + 1) * 64 + c0 * 8);
                vb4[i] = *reinterpret_cast<const uint4*>(wb + (size_t)(cb + r0 + 32 * i) * HIDDEN + (kt + 1) * 64 + c0 * 8);
            }
        }
#pragma unroll
        for (int kk = 0; kk < 2; kk++) {
            bf16x8 a[4], b[4];
#pragma unroll
            for (int mi = 0; mi < 4; mi++) {
                int row = wr * 64 + mi * 16 + (lane & 15);
                a[mi] = *reinterpret_cast<const bf16x8*>(As[cur] + row * 64 + (((kk * 4 + (lane >> 4)) ^ (row & 7)) << 3));
            }
#pragma unroll
            for (int ni = 0; ni < 4; ni++) {
                int row = wc * 64 + ni * 16 + (lane & 15);
                b[ni] = *reinterpret_cast<const bf16x8*>(Bs[cur] + row * 64 + (((kk * 4 + (lane >> 4)) ^ (row & 7)) << 3));
            }
#pragma unroll
            for (int mi = 0; mi < 4; mi++)
#pragma unroll
                for (int ni = 0; ni < 4; ni++)
                    acc[mi][ni] = __builtin_amdgcn_mfma_f32_16x16x32_bf16(a[mi], b[ni], acc[mi][ni], 0, 0, 0);
        }
        if (kt < 15) {
#pragma unroll
            for (int i = 0; i < 4; i++) {
                int row = r0 + 32 * i;
                *reinterpret_cast<uint4*>(As[cur ^ 1] + row * 64 + ((c0 ^ (row & 7)) << 3)) = va[i];
                *reinterpret_cast<uint4*>(Bs[cur ^ 1] + row * 64 + ((c0 ^ (row & 7)) << 3)) = vb4[i];
            }
        }
        __syncthreads();
        cur ^= 1;
    }

    const int region = blockIdx.x >> 3;  // 0=q, 1=k, 2=v
    const float* bias = region == 0 ? bq : (region == 1 ? bk : bv);
    unsigned short* dst = region == 0 ? qb : kb;
#pragma unroll
    for (int mi = 0; mi < 4; mi++) {
#pragma unroll
        for (int ni = 0; ni < 4; ni++) {
            int colg = cb + wc * 64 + ni * 16 + (lane & 15);
            int jj = colg & 1023;
            int hh = jj >> 6, d = jj & 63;
            float bval = bias[jj];
#pragma unroll
            for (int r = 0; r < 4; r++) {
                int n = rb + wr * 64 + mi * 16 + ((lane >> 4) << 2) + r;
                unsigned short val = f2bf(acc[mi][ni][r] + bval);
                if (region < 2)
                    dst[((size_t)hh * N_TOK + n) * 64 + d] = val;
                else  // v: tiled layout vt[((h*64 + n/32)*64 + d)*32 + n%32]
                    vt[(((size_t)(hh * 64 + (n >> 5)) * 64 + d) * 32) + (n & 31)] = val;
            }
        }
    }
}

// ---------------- K2: fused attention — deep-pipelined gl_lds dbuf, counted vmcnt ----------------
// 32-col tiles, 64 tiles, two passes. LDS: K 2x4KB | V 2x4KB | P 1KB = 17KB.
// hist prefetch 2-deep (parity reg sets, no copies); stores deferred 2 tiles.
__launch_bounds__(64, 2)
__global__ void attn_fused(const unsigned short* __restrict__ qb,
                           const unsigned short* __restrict__ kb,
                           const unsigned short* __restrict__ vt,
                           const float* __restrict__ hist,
                           const float* __restrict__ beta_p,
                           float* __restrict__ attn_out,
                           float* __restrict__ nh_out,
                           float* __restrict__ hv) {
    __shared__ unsigned short Kbuf[2][2048];
    __shared__ unsigned short Vbuf[2][2048];
    __shared__ unsigned short Psw[512];
    const int lane = threadIdx.x;
    const int g = lane >> 4, q15 = lane & 15;
    // XCD swizzle: each XCD gets 2 consecutive heads
    const int bid = blockIdx.x;
    const int orig = (bid & 7) * 256 + (bid >> 3);
    const int h = orig >> 7, rb = orig & 127;
    const float beta = beta_p[0];
    const float scale = 0.125f;

    const unsigned short* qsrc = qb + ((size_t)h * N_TOK + rb * 16 + q15) * 64;
    bf16x8 aq0 = *reinterpret_cast<const bf16x8*>(qsrc + 8 * g);
    bf16x8 aq1 = *reinterpret_cast<const bf16x8*>(qsrc + 8 * g + 32);

    // staging: linear LDS dest; inverse-swizzled per-lane SOURCE (rule #21)
    const int koff = (lane >> 3) * 64 + (((lane & 7) ^ (lane >> 3)) << 3);          // shorts
    const int voff = (lane >> 2) * 32 + (((lane & 3) ^ ((lane >> 3) & 3)) << 3);    // shorts
    const unsigned short* kt0 = kb + (size_t)h * N_TOK * 64;  // + t*2048
    const unsigned short* vt0 = vt + (size_t)h * N_TOK * 64;  // + t*2048 (pre-tiled [t][d][32])

#define STAGE_K(T, B) do { const unsigned short* _s = kt0 + (size_t)(T) * 2048 + koff; \
        gl_lds16(_s,        &Kbuf[B][0]);    gl_lds16(_s + 512,  &Kbuf[B][512]);   \
        gl_lds16(_s + 1024, &Kbuf[B][1024]); gl_lds16(_s + 1536, &Kbuf[B][1536]); } while (0)
#define STAGE_V(T, B) do { const unsigned short* _s = vt0 + (size_t)(T) * 2048 + voff; \
        gl_lds16(_s,        &Vbuf[B][0]);    gl_lds16(_s + 512,  &Vbuf[B][512]);   \
        gl_lds16(_s + 1024, &Vbuf[B][1024]); gl_lds16(_s + 1536, &Vbuf[B][1536]); } while (0)

    const size_t rowbase = ((size_t)h * N_TOK + rb * 16 + q15) * N_TOK;
    const float* hbase = hist + rowbase + 4 * g;
    float* abase = attn_out + rowbase + 4 * g;
    float* nbase = nh_out + rowbase + 4 * g;

    float m = -1e30f, l = 0.0f;
    f32x4 h4[2][2];   // [parity set][nt] — static indices under unroll-2

    // ---- pass 1 prologue: stage K(0); hist(0)->set0, hist(1)->set1 (2-deep) ----
    STAGE_K(0, 0);
    h4[0][0] = *reinterpret_cast<const f32x4*>(hbase);
    h4[0][1] = *reinterpret_cast<const f32x4*>(hbase + 16);
    h4[1][0] = *reinterpret_cast<const f32x4*>(hbase + 32);
    h4[1][1] = *reinterpret_cast<const f32x4*>(hbase + 48);

    // ---- pass 1: stats ----
#pragma unroll 2
    for (int t = 0; t < 64; ++t) {
        const int cur = t & 1;
        const int tn = (t < 63) ? (t + 1) : 63;
        STAGE_K(tn, tn & 1);
        WAITV(6);  // retire stage(t)+hist(t); keep hist(t+1), stage(t+1) in flight
        f32x4 s_acc[2];
#pragma unroll
        for (int nt = 0; nt < 2; ++nt) {
            int krow = nt * 16 + q15;
            bf16x8 kf0 = *reinterpret_cast<const bf16x8*>(Kbuf[cur] + krow * 64 + ((g ^ (q15 & 7)) << 3));
            bf16x8 kf1 = *reinterpret_cast<const bf16x8*>(Kbuf[cur] + krow * 64 + (((4 + g) ^ (q15 & 7)) << 3));
            s_acc[nt] = __builtin_amdgcn_mfma_f32_16x16x32_bf16(kf0, aq0, zero4(), 0, 0, 0);
            s_acc[nt] = __builtin_amdgcn_mfma_f32_16x16x32_bf16(kf1, aq1, s_acc[nt], 0, 0, 0);
        }
        float sc[2][4];
#pragma unroll
        for (int nt = 0; nt < 2; ++nt)
#pragma unroll
            for (int r = 0; r < 4; ++r)
                sc[nt][r] = s_acc[nt][r] * scale + beta * h4[cur][nt][r];

        // re-issue hist(t+2) into the just-consumed set (no copies)
        {
            const int hp = (t < 62) ? (t + 2) : 63;
            h4[cur][0] = *reinterpret_cast<const f32x4*>(hbase + hp * 32);
            h4[cur][1] = *reinterpret_cast<const f32x4*>(hbase + hp * 32 + 16);
        }

        float tm = sc[0][0];
#pragma unroll
        for (int nt = 0; nt < 2; ++nt)
#pragma unroll
            for (int r = 0; r < 4; ++r) tm = fmaxf(tm, sc[nt][r]);
        tm = fmaxf(tm, __shfl_xor(tm, 16));
        tm = fmaxf(tm, __shfl_xor(tm, 32));
        float mn = fmaxf(m, tm);
        float ps = 0.0f;
#pragma unroll
        for (int nt = 0; nt < 2; ++nt)
#pragma unroll
            for (int r = 0; r < 4; ++r) ps += __expf(sc[nt][r] - mn);
        ps += __shfl_xor(ps, 16);
        ps += __shfl_xor(ps, 32);
        l = l * __expf(m - mn) + ps;
        m = mn;
    }
    const float inv_l = 1.0f / l;

    f32x4 oacc[4];
#pragma unroll
    for (int di = 0; di < 4; ++di) oacc[di] = zero4();

    f32x4 sA[2][2], sN[2][2];  // deferred NT-store payloads, by body parity

    // pass-2 compute body: tile T from buf CUR; hist/store set P; reissue hist(HP)
#define P2_BODY(T, CUR, P, HP) do { \
        f32x4 s_acc[2]; \
        _Pragma("unroll") \
        for (int nt = 0; nt < 2; ++nt) { \
            int krow = nt * 16 + q15; \
            bf16x8 kf0 = *reinterpret_cast<const bf16x8*>(Kbuf[CUR] + krow * 64 + ((g ^ (q15 & 7)) << 3)); \
            bf16x8 kf1 = *reinterpret_cast<const bf16x8*>(Kbuf[CUR] + krow * 64 + (((4 + g) ^ (q15 & 7)) << 3)); \
            s_acc[nt] = __builtin_amdgcn_mfma_f32_16x16x32_bf16(kf0, aq0, zero4(), 0, 0, 0); \
            s_acc[nt] = __builtin_amdgcn_mfma_f32_16x16x32_bf16(kf1, aq1, s_acc[nt], 0, 0, 0); \
        } \
        _Pragma("unroll") \
        for (int nt = 0; nt < 2; ++nt) { \
            float a0 = __expf(s_acc[nt][0] * scale + beta * h4[P][nt][0] - m) * inv_l; \
            float a1 = __expf(s_acc[nt][1] * scale + beta * h4[P][nt][1] - m) * inv_l; \
            float a2 = __expf(s_acc[nt][2] * scale + beta * h4[P][nt][2] - m) * inv_l; \
            float a3 = __expf(s_acc[nt][3] * scale + beta * h4[P][nt][3] - m) * inv_l; \
            f32x4 av, nv; \
            av[0] = a0; av[1] = a1; av[2] = a2; av[3] = a3; \
            nv[0] = a0 + h4[P][nt][0]; nv[1] = a1 + h4[P][nt][1]; \
            nv[2] = a2 + h4[P][nt][2]; nv[3] = a3 + h4[P][nt][3]; \
            sA[P][nt] = av; sN[P][nt] = nv; \
            ushort4 p; \
            p.x = f2bf(a0); p.y = f2bf(a1); p.z = f2bf(a2); p.w = f2bf(a3); \
            *reinterpret_cast<ushort4*>(Psw + q15 * 32 + (((4 * nt + g) ^ (q15 & 6)) << 2)) = p; \
        } \
        h4[P][0] = *reinterpret_cast<const f32x4*>(hbase + (HP) * 32); \
        h4[P][1] = *reinterpret_cast<const f32x4*>(hbase + (HP) * 32 + 16); \
        { \
            bf16x8 pa = *reinterpret_cast<const bf16x8*>(Psw + q15 * 32 + (((2 * g) ^ (q15 & 6)) << 2)); \
            _Pragma("unroll") \
            for (int di = 0; di < 4; ++di) { \
                int vrow = di * 16 + q15; \
                bf16x8 vf = *reinterpret_cast<const bf16x8*>(Vbuf[CUR] + vrow * 32 + ((g ^ ((q15 >> 1) & 3)) << 3)); \
                oacc[di] = __builtin_amdgcn_mfma_f32_16x16x32_bf16(pa, vf, oacc[di], 0, 0, 0); \
            } \
        } \
    } while (0)

#define P2_STORE(P, T) do { \
        __builtin_nontemporal_store(sA[P][0], reinterpret_cast<f32x4*>(abase + (T) * 32)); \
        __builtin_nontemporal_store(sA[P][1], reinterpret_cast<f32x4*>(abase + (T) * 32 + 16)); \
        __builtin_nontemporal_store(sN[P][0], reinterpret_cast<f32x4*>(nbase + (T) * 32)); \
        __builtin_nontemporal_store(sN[P][1], reinterpret_cast<f32x4*>(nbase + (T) * 32 + 16)); \
    } while (0)

    // ---- pass 2 prologue: K(63) resident in Kbuf[1]; stage V(63); hist(63)->set0, hist(62)->set1 ----
    STAGE_V(63, 1);
    h4[0][0] = *reinterpret_cast<const f32x4*>(hbase + 63 * 32);
    h4[0][1] = *reinterpret_cast<const f32x4*>(hbase + 63 * 32 + 16);
    h4[1][0] = *reinterpret_cast<const f32x4*>(hbase + 62 * 32);
    h4[1][1] = *reinterpret_cast<const f32x4*>(hbase + 62 * 32 + 16);

    // peeled body tt=0 (tile 63, buf 1, set 0)
    STAGE_K(62, 0); STAGE_V(62, 0);
    WAITV(10);
    P2_BODY(63, 1, 0, 61);
    // peeled body tt=1 (tile 62, buf 0, set 1)
    STAGE_K(61, 1); STAGE_V(61, 1);
    WAITV(10);
    P2_BODY(62, 0, 1, 60);

    // ---- pass 2 main: tt = 2..63 (tile t = 63-tt), reverse order for L2/L3 hist reuse ----
#pragma unroll 2
    for (int tt = 2; tt < 64; ++tt) {
        const int t = 63 - tt;
        const int p = tt & 1;          // hist/store set
        const int cur = t & 1;         // K/V buffer (== p^1)
        P2_STORE(p, t + 2);            // stores of tile t+2 (saved at body tt-2)
        const int tn = (t > 1) ? (t - 1) : 0;
        STAGE_K(tn, tn & 1); STAGE_V(tn, tn & 1);
        WAITV(14);                     // retire stage(t)+hist(t); keep stores+stage(t-1)+hist 2-deep
        const int hp = (t >= 2) ? (t - 2) : 0;
        P2_BODY(t, cur, p, hp);
    }
    // final stores: tile 1 (parity 0, saved at tt=62), tile 0 (parity 1, saved at tt=63)
    P2_STORE(0, 1);
    P2_STORE(1, 0);

    // epilogue: hv write
#pragma unroll
    for (int di = 0; di < 4; ++di) {
#pragma unroll
        for (int r = 0; r < 4; ++r) {
            int rl = g * 4 + r;
            int d = di * 16 + q15;
            hv[((size_t)h * N_TOK + rb * 16 + rl) * 64 + d] = oacc[di][r];
        }
    }
#undef STAGE_K
#undef STAGE_V
#undef P2_BODY
#undef P2_STORE
}

// ---------------- K3: output projection ----------------
__launch_bounds__(256)
__global__ void out_proj(const float* __restrict__ hv, const float* __restrict__ Wo,
                         const float* __restrict__ bo, float* __restrict__ out) {
    __shared__ float wos[64][129];
    const int tid = threadIdx.x;
    const int dd = tid & 63;
    const int w = tid >> 6;
    const int n0 = blockIdx.x * 16;
    float acc[4] = {0.f, 0.f, 0.f, 0.f};
    for (int kc = 0; kc < 1024; kc += 128) {
        __syncthreads();
#pragma unroll
        for (int i = 0; i < 32; i++) {
            int e = tid + 256 * i;
            int r = e >> 7, j = e & 127;
            wos[r][j] = Wo[(size_t)r * 1024 + kc + j];
        }
        __syncthreads();
#pragma unroll 4
        for (int k = 0; k < 128; k++) {
            float wv = wos[dd][k];
            int jg = kc + k;
            const float* hb = hv + ((size_t)(jg >> 6) * N_TOK) * 64 + (jg & 63);
#pragma unroll
            for (int q = 0; q < 4; q++) {
                acc[q] += hb[(size_t)(n0 + w + 4 * q) * 64] * wv;
            }
        }
    }
#pragma unroll
    for (int q = 0; q < 4; q++)
        out[(size_t)(n0 + w + 4 * q) * 64 + dd] = acc[q] + bo[dd];
}

extern "C" void kernel_launch(void* const* d_in, const int* in_sizes, int n_in,
                              void* d_out, int out_size, void* d_ws, size_t ws_size,
                              hipStream_t stream) {
    const float* x    = (const float*)d_in[0];
    const float* hist = (const float*)d_in[1];
    const float* Wq_w = (const float*)d_in[2];
    const float* Wq_b = (const float*)d_in[3];
    const float* Wk_w = (const float*)d_in[4];
    const float* Wk_b = (const float*)d_in[5];
    const float* Wv_w = (const float*)d_in[6];
    const float* Wv_b = (const float*)d_in[7];
    const float* Wo_w = (const float*)d_in[8];
    const float* Wo_b = (const float*)d_in[9];
    const float* beta = (const float*)d_in[10];

    float* out = (float*)d_out;
    float* attn_out = out + 131072;
    float* nh_out = attn_out + (size_t)NHEAD * N_TOK * N_TOK;

    unsigned short* xb  = (unsigned short*)d_ws;                 // 2M shorts
    unsigned short* wb  = xb + (size_t)N_TOK * HIDDEN;           // 3M shorts
    unsigned short* qb  = wb + (size_t)3 * HIDDEN * HIDDEN;      // 2M
    unsigned short* kb  = qb + (size_t)N_TOK * HIDDEN;
    unsigned short* vt  = kb + (size_t)N_TOK * HIDDEN;
    float* hvb = (float*)(vt + (size_t)N_TOK * HIDDEN);          // 2M f32

    cvt4_kernel<<<5120, 256, 0, stream>>>(x, Wq_w, Wk_w, Wv_w, xb);
    gemm_qkv<<<dim3(24, 16), 256, 0, stream>>>(xb, wb, Wq_b, Wk_b, Wv_b, qb, kb, vt);
    attn_fused<<<2048, 64, 0, stream>>>(qb, kb, vt, hist, beta, attn_out, nh_out, hvb);
    out_proj<<<128, 256, 0, stream>>>(hvb, Wo_w, Wo_b, out);
}